// Round 1
// baseline (12407.871 us; speedup 1.0000x reference)
//
#include <hip/hip_runtime.h>
#include <hip/hip_bf16.h>

#define HIDDEN 256
#define IN_CH 128

// ---------------- degree / dinv ----------------
__global__ void k_deg(const int* __restrict__ dst, int* __restrict__ deg, int E) {
    int e = blockIdx.x * blockDim.x + threadIdx.x;
    if (e < E) atomicAdd(&deg[dst[e]], 1);
}

__global__ void k_dinv(const int* __restrict__ deg, float* __restrict__ dinv, int N) {
    int n = blockIdx.x * blockDim.x + threadIdx.x;
    if (n < N) dinv[n] = rsqrtf((float)deg[n] + 1.0f);  // +1 self loop
}

// ---------------- GEMM: C[M,256] = A[M,K] @ W[K,256] + bias ----------------
template<int K>
__global__ __launch_bounds__(256) void k_gemm_bias(const float* __restrict__ A,
        const float* __restrict__ W, const float* __restrict__ bias,
        float* __restrict__ C, int M) {
    __shared__ float As[32 * K];
    __shared__ float Bs[32 * 256];
    const int tid = threadIdx.x;
    const int m0 = blockIdx.x * 32;
    const int rows = (M - m0 < 32) ? (M - m0) : 32;

    const float4* A4 = reinterpret_cast<const float4*>(A + (size_t)m0 * K);
    float4* As4 = reinterpret_cast<float4*>(As);
    const int AT4 = 32 * K / 4;
    for (int i = tid; i < AT4; i += 256) {
        int r = i / (K / 4);
        As4[i] = (r < rows) ? A4[i] : make_float4(0.f, 0.f, 0.f, 0.f);
    }

    float acc[32];
#pragma unroll
    for (int m = 0; m < 32; ++m) acc[m] = 0.f;

    float4* Bs4 = reinterpret_cast<float4*>(Bs);
    for (int kc = 0; kc < K; kc += 32) {
        __syncthreads();
        const float4* B4 = reinterpret_cast<const float4*>(W + (size_t)kc * 256);
        for (int i = tid; i < 32 * 256 / 4; i += 256) Bs4[i] = B4[i];
        __syncthreads();
        for (int k = 0; k < 32; k += 4) {
            float b0 = Bs[(k + 0) * 256 + tid];
            float b1 = Bs[(k + 1) * 256 + tid];
            float b2 = Bs[(k + 2) * 256 + tid];
            float b3 = Bs[(k + 3) * 256 + tid];
#pragma unroll
            for (int m = 0; m < 32; ++m) {
                float4 a = As4[m * (K / 4) + (kc + k) / 4];
                acc[m] = fmaf(a.x, b0, acc[m]);
                acc[m] = fmaf(a.y, b1, acc[m]);
                acc[m] = fmaf(a.z, b2, acc[m]);
                acc[m] = fmaf(a.w, b3, acc[m]);
            }
        }
    }
    float bv = bias[tid];
    for (int m = 0; m < rows; ++m)
        C[(size_t)(m0 + m) * 256 + tid] = acc[m] + bv;
}

// ---------------- row scale (optional relu), float4 granularity ----------------
__global__ void k_rowscale(float* __restrict__ X, const float* __restrict__ dinv,
                           int n4, int relu) {
    int i = blockIdx.x * blockDim.x + threadIdx.x;
    if (i >= n4) return;
    float4 v = reinterpret_cast<float4*>(X)[i];
    float s = dinv[i >> 6];  // 64 float4 per row of 256
    v.x *= s; v.y *= s; v.z *= s; v.w *= s;
    if (relu) {
        v.x = fmaxf(v.x, 0.f); v.y = fmaxf(v.y, 0.f);
        v.z = fmaxf(v.z, 0.f); v.w = fmaxf(v.w, 0.f);
    }
    reinterpret_cast<float4*>(X)[i] = v;
}

// ---------------- edge scatter-add: acc[dst] += Y[src], one wave/edge ----------------
__global__ void k_edge_agg(const float* __restrict__ Y, float* __restrict__ acc,
                           const int* __restrict__ src, const int* __restrict__ dst, int E) {
    int wid = threadIdx.x >> 6;
    int lane = threadIdx.x & 63;
    int e = blockIdx.x * 4 + wid;
    if (e >= E) return;
    int s = src[e], d = dst[e];
    float4 v = reinterpret_cast<const float4*>(Y + (size_t)s * 256)[lane];
    float* a = acc + (size_t)d * 256 + lane * 4;
    unsafeAtomicAdd(a + 0, v.x);
    unsafeAtomicAdd(a + 1, v.y);
    unsafeAtomicAdd(a + 2, v.z);
    unsafeAtomicAdd(a + 3, v.w);
}

// ---------------- transpose 256x256: Wout[k][j] = Win[j][k] ----------------
__global__ void k_transpose256(const float* __restrict__ Win, float* __restrict__ Wout) {
    int j = threadIdx.x, k = blockIdx.x;
    Wout[k * 256 + j] = Win[j * 256 + k];
}

// ---------------- wsum[c] = sum_j opw[j][c];  bsum = sum(opb) ----------------
__global__ void k_wsum(const float* __restrict__ opw, const float* __restrict__ opb,
                       float* __restrict__ wsum, float* __restrict__ bsum) {
    int c = threadIdx.x;
    float s = 0.f;
    for (int j = 0; j < 256; ++j) s += opw[j * 256 + c];
    wsum[c] = s;
    __shared__ float red[256];
    red[c] = opb[c];
    __syncthreads();
    for (int st = 128; st > 0; st >>= 1) {
        if (c < st) red[c] += red[c + st];
        __syncthreads();
    }
    if (c == 0) *bsum = red[0];
}

// ---------------- wv_eff[h][k] = sum_{c in head h} wsum[h*64+c] * Wv[h*64+c][k] ----------------
__global__ void k_wveff(const float* __restrict__ ipw, const float* __restrict__ ipb,
                        const float* __restrict__ wsum, float* __restrict__ wv_eff,
                        float* __restrict__ vconst) {
    int h = blockIdx.x, k = threadIdx.x;
    float s = 0.f;
    for (int c = 0; c < 64; ++c)
        s += wsum[h * 64 + c] * ipw[(size_t)(512 + h * 64 + c) * 256 + k];
    wv_eff[h * 256 + k] = s;
    if (k == 0) {
        float t = 0.f;
        for (int c = 0; c < 64; ++c) t += ipb[512 + h * 64 + c] * wsum[h * 64 + c];
        vconst[h] = t;
    }
}

// ---------------- per-node: qk_self[n][h], vw[n][h] ----------------
__global__ void k_node_aux(const float* __restrict__ Q, const float* __restrict__ Km,
                           const float* __restrict__ Z, const float* __restrict__ wv_eff,
                           const float* __restrict__ vconst,
                           float* __restrict__ qk_self, float* __restrict__ vw, int N) {
    int wid = threadIdx.x >> 6, lane = threadIdx.x & 63;
    int n = blockIdx.x * 4 + wid;
    if (n >= N) return;
    float4 q = reinterpret_cast<const float4*>(Q + (size_t)n * 256)[lane];
    float4 k = reinterpret_cast<const float4*>(Km + (size_t)n * 256)[lane];
    float4 z = reinterpret_cast<const float4*>(Z + (size_t)n * 256)[lane];
    float p = q.x * k.x + q.y * k.y + q.z * k.z + q.w * k.w;
    for (int st = 1; st < 16; st <<= 1) p += __shfl_xor(p, st);
    if ((lane & 15) == 0) qk_self[n * 4 + (lane >> 4)] = p;

    float ph0, ph1, ph2, ph3;
    {
        float4 w;
        w = reinterpret_cast<const float4*>(wv_eff + 0 * 256)[lane];
        ph0 = z.x * w.x + z.y * w.y + z.z * w.z + z.w * w.w;
        w = reinterpret_cast<const float4*>(wv_eff + 1 * 256)[lane];
        ph1 = z.x * w.x + z.y * w.y + z.z * w.z + z.w * w.w;
        w = reinterpret_cast<const float4*>(wv_eff + 2 * 256)[lane];
        ph2 = z.x * w.x + z.y * w.y + z.z * w.z + z.w * w.w;
        w = reinterpret_cast<const float4*>(wv_eff + 3 * 256)[lane];
        ph3 = z.x * w.x + z.y * w.y + z.z * w.z + z.w * w.w;
    }
    for (int st = 1; st < 64; st <<= 1) {
        ph0 += __shfl_xor(ph0, st);
        ph1 += __shfl_xor(ph1, st);
        ph2 += __shfl_xor(ph2, st);
        ph3 += __shfl_xor(ph3, st);
    }
    if (lane == 0) {
        vw[n * 4 + 0] = ph0 + vconst[0];
        vw[n * 4 + 1] = ph1 + vconst[1];
        vw[n * 4 + 2] = ph2 + vconst[2];
        vw[n * 4 + 3] = ph3 + vconst[3];
    }
}

// ---------------- per pred-edge final ----------------
__global__ void k_edge_pred(const float* __restrict__ Q, const float* __restrict__ Km,
                            const float* __restrict__ qk_self, const float* __restrict__ vw,
                            const float* __restrict__ bsum, const int* __restrict__ sp,
                            const int* __restrict__ dp, float* __restrict__ out, int E) {
    int wid = threadIdx.x >> 6, lane = threadIdx.x & 63;
    int e = blockIdx.x * 4 + wid;
    if (e >= E) return;
    int s = sp[e], d = dp[e];
    float4 q = reinterpret_cast<const float4*>(Q + (size_t)s * 256)[lane];
    float4 k = reinterpret_cast<const float4*>(Km + (size_t)d * 256)[lane];
    float p = q.x * k.x + q.y * k.y + q.z * k.z + q.w * k.w;
    for (int st = 1; st < 16; st <<= 1) p += __shfl_xor(p, st);
    int h = lane >> 4;
    const float scale = 0.125f;
    float s1 = p * scale;
    float s0 = qk_self[s * 4 + h] * scale;
    float vs = vw[s * 4 + h], vd = vw[d * 4 + h];
    float m = fmaxf(s0, s1);
    float e0 = expf(s0 - m), e1 = expf(s1 - m);
    float contrib = (e0 * vs + e1 * vd) / (e0 + e1);
    contrib += __shfl_xor(contrib, 16);
    contrib += __shfl_xor(contrib, 32);
    if (lane == 0) out[e] = 1.f / (1.f + expf(-(contrib + *bsum)));
}

extern "C" void kernel_launch(void* const* d_in, const int* in_sizes, int n_in,
                              void* d_out, int out_size, void* d_ws, size_t ws_size,
                              hipStream_t stream) {
    const float* x   = (const float*)d_in[0];
    const int*   ei  = (const int*)d_in[1];
    const int*   eip = (const int*)d_in[2];
    const float* W1  = (const float*)d_in[3];
    const float* b1  = (const float*)d_in[4];
    const float* W2  = (const float*)d_in[5];
    const float* b2  = (const float*)d_in[6];
    const float* ipw = (const float*)d_in[7];
    const float* ipb = (const float*)d_in[8];
    const float* opw = (const float*)d_in[9];
    const float* opb = (const float*)d_in[10];
    float* out = (float*)d_out;

    const int N = in_sizes[0] / IN_CH;      // 50000
    const int E = in_sizes[1] / 2;          // 1.6M
    const int EP = in_sizes[2] / 2;         // 500K

    // workspace layout (floats)
    float* wsf = (float*)d_ws;
    size_t o = 0;
    int*   deg     = (int*)(wsf + o); o += N;
    float* dinv    = wsf + o; o += N;
    float* wsum    = wsf + o; o += 256;
    float* bsum    = wsf + o; o += 4;
    float* wv_eff  = wsf + o; o += 1024;
    float* vconst  = wsf + o; o += 4;
    float* Wqt     = wsf + o; o += 256 * 256;
    float* Wkt     = wsf + o; o += 256 * 256;
    float* qk_self = wsf + o; o += (size_t)4 * N;
    float* vw      = wsf + o; o += (size_t)4 * N;
    float* A       = wsf + o; o += (size_t)N * 256;
    float* B       = wsf + o; o += (size_t)N * 256;
    float* Cb      = wsf + o; o += (size_t)N * 256;
    (void)ws_size; (void)n_in; (void)out_size;

    const int* src = ei;
    const int* dst = ei + E;

    hipMemsetAsync(deg, 0, (size_t)N * 4, stream);
    k_deg<<<(E + 255) / 256, 256, 0, stream>>>(dst, deg, E);
    k_dinv<<<(N + 255) / 256, 256, 0, stream>>>(deg, dinv, N);

    // small precomputes (independent of GCN)
    k_transpose256<<<256, 256, 0, stream>>>(ipw, Wqt);
    k_transpose256<<<256, 256, 0, stream>>>(ipw + 256 * 256, Wkt);
    k_wsum<<<1, 256, 0, stream>>>(opw, opb, wsum, bsum);
    k_wveff<<<4, 256, 0, stream>>>(ipw, ipb, wsum, wv_eff, vconst);

    const int gBlocks = (N + 31) / 32;
    const int n4 = N * 64;

    // ---- layer 1 ----
    k_gemm_bias<128><<<gBlocks, 256, 0, stream>>>(x, W1, b1, A, N);
    k_rowscale<<<(n4 + 255) / 256, 256, 0, stream>>>(A, dinv, n4, 0);     // A = Y1
    hipMemcpyAsync(B, A, (size_t)N * 256 * 4, hipMemcpyDeviceToDevice, stream);
    k_edge_agg<<<(E + 3) / 4, 256, 0, stream>>>(A, B, src, dst, E);
    k_rowscale<<<(n4 + 255) / 256, 256, 0, stream>>>(B, dinv, n4, 1);     // B = h

    // ---- layer 2 ----
    k_gemm_bias<256><<<gBlocks, 256, 0, stream>>>(B, W2, b2, Cb, N);
    k_rowscale<<<(n4 + 255) / 256, 256, 0, stream>>>(Cb, dinv, n4, 0);    // Cb = Y2
    hipMemcpyAsync(A, Cb, (size_t)N * 256 * 4, hipMemcpyDeviceToDevice, stream);
    k_edge_agg<<<(E + 3) / 4, 256, 0, stream>>>(Cb, A, src, dst, E);
    k_rowscale<<<(n4 + 255) / 256, 256, 0, stream>>>(A, dinv, n4, 0);     // A = z

    // ---- attention precompute ----
    k_gemm_bias<256><<<gBlocks, 256, 0, stream>>>(A, Wqt, ipb, B, N);        // B = Q
    k_gemm_bias<256><<<gBlocks, 256, 0, stream>>>(A, Wkt, ipb + 256, Cb, N); // Cb = K
    k_node_aux<<<(N + 3) / 4, 256, 0, stream>>>(B, Cb, A, wv_eff, vconst, qk_self, vw, N);

    // ---- per pred edge ----
    k_edge_pred<<<(EP + 3) / 4, 256, 0, stream>>>(B, Cb, qk_self, vw, bsum,
                                                  eip, eip + EP, out, EP);
}

// Round 2
// 1590.667 us; speedup vs baseline: 7.8004x; 7.8004x over previous
//
#include <hip/hip_runtime.h>
#include <hip/hip_bf16.h>

#define HIDDEN 256
#define IN_CH 128

// ---------------- degree ----------------
__global__ void k_deg(const int* __restrict__ dst, int* __restrict__ deg, int E) {
    int e = blockIdx.x * blockDim.x + threadIdx.x;
    if (e < E) atomicAdd(&deg[dst[e]], 1);
}

__global__ void k_dinv(const int* __restrict__ deg, float* __restrict__ dinv, int N) {
    int n = blockIdx.x * blockDim.x + threadIdx.x;
    if (n < N) dinv[n] = rsqrtf((float)deg[n] + 1.0f);  // +1 self loop
}

// ---------------- hierarchical exclusive prefix scan of deg -> offs ----------------
__global__ void k_chunksum(const int* __restrict__ deg, int* __restrict__ part, int N) {
    __shared__ int sh[256];
    int i = blockIdx.x * 256 + threadIdx.x;
    sh[threadIdx.x] = (i < N) ? deg[i] : 0;
    __syncthreads();
    for (int st = 128; st > 0; st >>= 1) {
        if (threadIdx.x < st) sh[threadIdx.x] += sh[threadIdx.x + st];
        __syncthreads();
    }
    if (threadIdx.x == 0) part[blockIdx.x] = sh[0];
}

__global__ void k_scanpart(int* __restrict__ part, int nb) {
    // single block of 256, exclusive scan in place (nb <= 256)
    __shared__ int sh[256];
    int v = (threadIdx.x < nb) ? part[threadIdx.x] : 0;
    sh[threadIdx.x] = v;
    __syncthreads();
    for (int st = 1; st < 256; st <<= 1) {
        int t = (threadIdx.x >= st) ? sh[threadIdx.x - st] : 0;
        __syncthreads();
        sh[threadIdx.x] += t;
        __syncthreads();
    }
    if (threadIdx.x < nb) part[threadIdx.x] = sh[threadIdx.x] - v;
}

__global__ void k_scanfinal(const int* __restrict__ deg, const int* __restrict__ part,
                            int* __restrict__ offs, int N, int E) {
    __shared__ int sh[256];
    int i = blockIdx.x * 256 + threadIdx.x;
    int v = (i < N) ? deg[i] : 0;
    sh[threadIdx.x] = v;
    __syncthreads();
    for (int st = 1; st < 256; st <<= 1) {
        int t = (threadIdx.x >= st) ? sh[threadIdx.x - st] : 0;
        __syncthreads();
        sh[threadIdx.x] += t;
        __syncthreads();
    }
    if (i < N) offs[i] = part[blockIdx.x] + sh[threadIdx.x] - v;
    if (i == 0) offs[N] = E;
}

// ---------------- counting-sort scatter: sorted_src grouped by dst ----------------
__global__ void k_scatter(const int* __restrict__ src, const int* __restrict__ dst,
                          const int* __restrict__ offs, int* __restrict__ cursor,
                          int* __restrict__ ssrc, int E) {
    int e = blockIdx.x * blockDim.x + threadIdx.x;
    if (e >= E) return;
    int d = dst[e];
    int p = offs[d] + atomicAdd(&cursor[d], 1);
    ssrc[p] = src[e];
}

// ---------------- GEMM: C[M,256] = (A[M,K] @ W[K,256] + bias) * rowscale? ----------------
template<int K>
__global__ __launch_bounds__(256) void k_gemm_bias(const float* __restrict__ A,
        const float* __restrict__ W, const float* __restrict__ bias,
        const float* __restrict__ rowscale,
        float* __restrict__ C, int M) {
    __shared__ float As[32 * K];
    __shared__ float Bs[32 * 256];
    const int tid = threadIdx.x;
    const int m0 = blockIdx.x * 32;
    const int rows = (M - m0 < 32) ? (M - m0) : 32;

    const float4* A4 = reinterpret_cast<const float4*>(A + (size_t)m0 * K);
    float4* As4 = reinterpret_cast<float4*>(As);
    const int AT4 = 32 * K / 4;
    for (int i = tid; i < AT4; i += 256) {
        int r = i / (K / 4);
        As4[i] = (r < rows) ? A4[i] : make_float4(0.f, 0.f, 0.f, 0.f);
    }

    float acc[32];
#pragma unroll
    for (int m = 0; m < 32; ++m) acc[m] = 0.f;

    float4* Bs4 = reinterpret_cast<float4*>(Bs);
    for (int kc = 0; kc < K; kc += 32) {
        __syncthreads();
        const float4* B4 = reinterpret_cast<const float4*>(W + (size_t)kc * 256);
        for (int i = tid; i < 32 * 256 / 4; i += 256) Bs4[i] = B4[i];
        __syncthreads();
        for (int k = 0; k < 32; k += 4) {
            float b0 = Bs[(k + 0) * 256 + tid];
            float b1 = Bs[(k + 1) * 256 + tid];
            float b2 = Bs[(k + 2) * 256 + tid];
            float b3 = Bs[(k + 3) * 256 + tid];
#pragma unroll
            for (int m = 0; m < 32; ++m) {
                float4 a = As4[m * (K / 4) + (kc + k) / 4];
                acc[m] = fmaf(a.x, b0, acc[m]);
                acc[m] = fmaf(a.y, b1, acc[m]);
                acc[m] = fmaf(a.z, b2, acc[m]);
                acc[m] = fmaf(a.w, b3, acc[m]);
            }
        }
    }
    float bv = bias[tid];
    for (int m = 0; m < rows; ++m) {
        float val = acc[m] + bv;
        if (rowscale) val *= rowscale[m0 + m];
        C[(size_t)(m0 + m) * 256 + tid] = val;
    }
}

// ---------------- gather aggregation: out[d] = post(dinv[d] * (Ys[d] + sum_bucket Ys[s])) ----------------
__global__ __launch_bounds__(256) void k_gather_agg(const float* __restrict__ Ys,
        const int* __restrict__ offs, const int* __restrict__ ssrc,
        const float* __restrict__ dinv, float* __restrict__ outp, int N, int relu) {
    int wid = threadIdx.x >> 6, lane = threadIdx.x & 63;
    int d = blockIdx.x * 4 + wid;
    if (d >= N) return;
    int beg = offs[d], end = offs[d + 1];
    float4 acc = reinterpret_cast<const float4*>(Ys + (size_t)d * 256)[lane];  // self loop
    int i = beg;
    for (; i + 4 <= end; i += 4) {
        int s0 = ssrc[i], s1 = ssrc[i + 1], s2 = ssrc[i + 2], s3 = ssrc[i + 3];
        float4 v0 = reinterpret_cast<const float4*>(Ys + (size_t)s0 * 256)[lane];
        float4 v1 = reinterpret_cast<const float4*>(Ys + (size_t)s1 * 256)[lane];
        float4 v2 = reinterpret_cast<const float4*>(Ys + (size_t)s2 * 256)[lane];
        float4 v3 = reinterpret_cast<const float4*>(Ys + (size_t)s3 * 256)[lane];
        acc.x += (v0.x + v1.x) + (v2.x + v3.x);
        acc.y += (v0.y + v1.y) + (v2.y + v3.y);
        acc.z += (v0.z + v1.z) + (v2.z + v3.z);
        acc.w += (v0.w + v1.w) + (v2.w + v3.w);
    }
    for (; i < end; ++i) {
        int s = ssrc[i];
        float4 v = reinterpret_cast<const float4*>(Ys + (size_t)s * 256)[lane];
        acc.x += v.x; acc.y += v.y; acc.z += v.z; acc.w += v.w;
    }
    float sc = dinv[d];
    acc.x *= sc; acc.y *= sc; acc.z *= sc; acc.w *= sc;
    if (relu) {
        acc.x = fmaxf(acc.x, 0.f); acc.y = fmaxf(acc.y, 0.f);
        acc.z = fmaxf(acc.z, 0.f); acc.w = fmaxf(acc.w, 0.f);
    }
    reinterpret_cast<float4*>(outp + (size_t)d * 256)[lane] = acc;
}

// ---------------- transpose 256x256: Wout[k][j] = Win[j][k] ----------------
__global__ void k_transpose256(const float* __restrict__ Win, float* __restrict__ Wout) {
    int j = threadIdx.x, k = blockIdx.x;
    Wout[k * 256 + j] = Win[j * 256 + k];
}

// ---------------- wsum[c] = sum_j opw[j][c];  bsum = sum(opb) ----------------
__global__ void k_wsum(const float* __restrict__ opw, const float* __restrict__ opb,
                       float* __restrict__ wsum, float* __restrict__ bsum) {
    int c = threadIdx.x;
    float s = 0.f;
    for (int j = 0; j < 256; ++j) s += opw[j * 256 + c];
    wsum[c] = s;
    __shared__ float red[256];
    red[c] = opb[c];
    __syncthreads();
    for (int st = 128; st > 0; st >>= 1) {
        if (c < st) red[c] += red[c + st];
        __syncthreads();
    }
    if (c == 0) *bsum = red[0];
}

// ---------------- wv_eff[h][k] = sum_{c in head h} wsum[h*64+c] * Wv[h*64+c][k] ----------------
__global__ void k_wveff(const float* __restrict__ ipw, const float* __restrict__ ipb,
                        const float* __restrict__ wsum, float* __restrict__ wv_eff,
                        float* __restrict__ vconst) {
    int h = blockIdx.x, k = threadIdx.x;
    float s = 0.f;
    for (int c = 0; c < 64; ++c)
        s += wsum[h * 64 + c] * ipw[(size_t)(512 + h * 64 + c) * 256 + k];
    wv_eff[h * 256 + k] = s;
    if (k == 0) {
        float t = 0.f;
        for (int c = 0; c < 64; ++c) t += ipb[512 + h * 64 + c] * wsum[h * 64 + c];
        vconst[h] = t;
    }
}

// ---------------- per-node: qk_self[n][h], vw[n][h] ----------------
__global__ void k_node_aux(const float* __restrict__ Q, const float* __restrict__ Km,
                           const float* __restrict__ Z, const float* __restrict__ wv_eff,
                           const float* __restrict__ vconst,
                           float* __restrict__ qk_self, float* __restrict__ vw, int N) {
    int wid = threadIdx.x >> 6, lane = threadIdx.x & 63;
    int n = blockIdx.x * 4 + wid;
    if (n >= N) return;
    float4 q = reinterpret_cast<const float4*>(Q + (size_t)n * 256)[lane];
    float4 k = reinterpret_cast<const float4*>(Km + (size_t)n * 256)[lane];
    float4 z = reinterpret_cast<const float4*>(Z + (size_t)n * 256)[lane];
    float p = q.x * k.x + q.y * k.y + q.z * k.z + q.w * k.w;
    for (int st = 1; st < 16; st <<= 1) p += __shfl_xor(p, st);
    if ((lane & 15) == 0) qk_self[n * 4 + (lane >> 4)] = p;

    float ph0, ph1, ph2, ph3;
    {
        float4 w;
        w = reinterpret_cast<const float4*>(wv_eff + 0 * 256)[lane];
        ph0 = z.x * w.x + z.y * w.y + z.z * w.z + z.w * w.w;
        w = reinterpret_cast<const float4*>(wv_eff + 1 * 256)[lane];
        ph1 = z.x * w.x + z.y * w.y + z.z * w.z + z.w * w.w;
        w = reinterpret_cast<const float4*>(wv_eff + 2 * 256)[lane];
        ph2 = z.x * w.x + z.y * w.y + z.z * w.z + z.w * w.w;
        w = reinterpret_cast<const float4*>(wv_eff + 3 * 256)[lane];
        ph3 = z.x * w.x + z.y * w.y + z.z * w.z + z.w * w.w;
    }
    for (int st = 1; st < 64; st <<= 1) {
        ph0 += __shfl_xor(ph0, st);
        ph1 += __shfl_xor(ph1, st);
        ph2 += __shfl_xor(ph2, st);
        ph3 += __shfl_xor(ph3, st);
    }
    if (lane == 0) {
        vw[n * 4 + 0] = ph0 + vconst[0];
        vw[n * 4 + 1] = ph1 + vconst[1];
        vw[n * 4 + 2] = ph2 + vconst[2];
        vw[n * 4 + 3] = ph3 + vconst[3];
    }
}

// ---------------- per pred-edge final ----------------
__global__ void k_edge_pred(const float* __restrict__ Q, const float* __restrict__ Km,
                            const float* __restrict__ qk_self, const float* __restrict__ vw,
                            const float* __restrict__ bsum, const int* __restrict__ sp,
                            const int* __restrict__ dp, float* __restrict__ out, int E) {
    int wid = threadIdx.x >> 6, lane = threadIdx.x & 63;
    int e = blockIdx.x * 4 + wid;
    if (e >= E) return;
    int s = sp[e], d = dp[e];
    float4 q = reinterpret_cast<const float4*>(Q + (size_t)s * 256)[lane];
    float4 k = reinterpret_cast<const float4*>(Km + (size_t)d * 256)[lane];
    float p = q.x * k.x + q.y * k.y + q.z * k.z + q.w * k.w;
    for (int st = 1; st < 16; st <<= 1) p += __shfl_xor(p, st);
    int h = lane >> 4;
    const float scale = 0.125f;
    float s1 = p * scale;
    float s0 = qk_self[s * 4 + h] * scale;
    float vs = vw[s * 4 + h], vd = vw[d * 4 + h];
    float m = fmaxf(s0, s1);
    float e0 = expf(s0 - m), e1 = expf(s1 - m);
    float contrib = (e0 * vs + e1 * vd) / (e0 + e1);
    contrib += __shfl_xor(contrib, 16);
    contrib += __shfl_xor(contrib, 32);
    if (lane == 0) out[e] = 1.f / (1.f + expf(-(contrib + *bsum)));
}

extern "C" void kernel_launch(void* const* d_in, const int* in_sizes, int n_in,
                              void* d_out, int out_size, void* d_ws, size_t ws_size,
                              hipStream_t stream) {
    const float* x   = (const float*)d_in[0];
    const int*   ei  = (const int*)d_in[1];
    const int*   eip = (const int*)d_in[2];
    const float* W1  = (const float*)d_in[3];
    const float* b1  = (const float*)d_in[4];
    const float* W2  = (const float*)d_in[5];
    const float* b2  = (const float*)d_in[6];
    const float* ipw = (const float*)d_in[7];
    const float* ipb = (const float*)d_in[8];
    const float* opw = (const float*)d_in[9];
    const float* opb = (const float*)d_in[10];
    float* out = (float*)d_out;

    const int N = in_sizes[0] / IN_CH;      // 50000
    const int E = in_sizes[1] / 2;          // 1.6M
    const int EP = in_sizes[2] / 2;         // 500K

    // workspace layout (floats), keep 16B alignment for float4 arrays
    float* wsf = (float*)d_ws;
    size_t o = 0;
    auto pad4 = [&](size_t v) { return (v + 3) & ~(size_t)3; };
    int*   deg     = (int*)(wsf + o); o += pad4(N);
    float* dinv    = wsf + o; o += pad4(N);
    float* wsum    = wsf + o; o += 256;
    float* bsum    = wsf + o; o += 4;
    float* wv_eff  = wsf + o; o += 1024;
    float* vconst  = wsf + o; o += 4;
    float* Wqt     = wsf + o; o += 256 * 256;
    float* Wkt     = wsf + o; o += 256 * 256;
    float* qk_self = wsf + o; o += pad4((size_t)4 * N);
    float* vw      = wsf + o; o += pad4((size_t)4 * N);
    int*   offs    = (int*)(wsf + o); o += pad4((size_t)N + 1);
    int*   cursor  = (int*)(wsf + o); o += pad4(N);
    int*   part    = (int*)(wsf + o); o += 256;
    int*   ssrc    = (int*)(wsf + o); o += pad4(E);
    float* A       = wsf + o; o += (size_t)N * 256;
    float* B       = wsf + o; o += (size_t)N * 256;
    float* Cb      = wsf + o; o += (size_t)N * 256;
    (void)ws_size; (void)n_in; (void)out_size;

    const int* src = ei;
    const int* dst = ei + E;
    const int nb = (N + 255) / 256;

    // ---- degree + dinv + CSR build (counting sort by dst) ----
    hipMemsetAsync(deg, 0, (size_t)N * 4, stream);
    hipMemsetAsync(cursor, 0, (size_t)N * 4, stream);
    k_deg<<<(E + 255) / 256, 256, 0, stream>>>(dst, deg, E);
    k_dinv<<<nb, 256, 0, stream>>>(deg, dinv, N);
    k_chunksum<<<nb, 256, 0, stream>>>(deg, part, N);
    k_scanpart<<<1, 256, 0, stream>>>(part, nb);
    k_scanfinal<<<nb, 256, 0, stream>>>(deg, part, offs, N, E);
    k_scatter<<<(E + 255) / 256, 256, 0, stream>>>(src, dst, offs, cursor, ssrc, E);

    // small precomputes (independent of GCN)
    k_transpose256<<<256, 256, 0, stream>>>(ipw, Wqt);
    k_transpose256<<<256, 256, 0, stream>>>(ipw + 256 * 256, Wkt);
    k_wsum<<<1, 256, 0, stream>>>(opw, opb, wsum, bsum);
    k_wveff<<<4, 256, 0, stream>>>(ipw, ipb, wsum, wv_eff, vconst);

    const int gBlocks = (N + 31) / 32;
    const int aBlocks = (N + 3) / 4;

    // ---- layer 1:  A = dinv*(x@W1+b1);  B = relu(dinv[d]*(A[d] + sum A[s])) ----
    k_gemm_bias<128><<<gBlocks, 256, 0, stream>>>(x, W1, b1, dinv, A, N);
    k_gather_agg<<<aBlocks, 256, 0, stream>>>(A, offs, ssrc, dinv, B, N, 1);

    // ---- layer 2:  Cb = dinv*(B@W2+b2);  A = z ----
    k_gemm_bias<256><<<gBlocks, 256, 0, stream>>>(B, W2, b2, dinv, Cb, N);
    k_gather_agg<<<aBlocks, 256, 0, stream>>>(Cb, offs, ssrc, dinv, A, N, 0);

    // ---- attention precompute: B = Q, Cb = K ----
    k_gemm_bias<256><<<gBlocks, 256, 0, stream>>>(A, Wqt, ipb, nullptr, B, N);
    k_gemm_bias<256><<<gBlocks, 256, 0, stream>>>(A, Wkt, ipb + 256, nullptr, Cb, N);
    k_node_aux<<<aBlocks, 256, 0, stream>>>(B, Cb, A, wv_eff, vconst, qk_self, vw, N);

    // ---- per pred edge ----
    k_edge_pred<<<(EP + 3) / 4, 256, 0, stream>>>(B, Cb, qk_self, vw, bsum,
                                                  eip, eip + EP, out, EP);
}

// Round 3
// 1249.928 us; speedup vs baseline: 9.9269x; 1.2726x over previous
//
#include <hip/hip_runtime.h>
#include <hip/hip_bf16.h>

#define HIDDEN 256
#define IN_CH 128

// ---------------- degree ----------------
__global__ void k_deg(const int* __restrict__ dst, int* __restrict__ deg, int E) {
    int e = blockIdx.x * blockDim.x + threadIdx.x;
    if (e < E) atomicAdd(&deg[dst[e]], 1);
}

__global__ void k_dinv(const int* __restrict__ deg, float* __restrict__ dinv, int N) {
    int n = blockIdx.x * blockDim.x + threadIdx.x;
    if (n < N) dinv[n] = rsqrtf((float)deg[n] + 1.0f);  // +1 self loop
}

// ---------------- hierarchical exclusive prefix scan of deg -> offs ----------------
__global__ void k_chunksum(const int* __restrict__ deg, int* __restrict__ part, int N) {
    __shared__ int sh[256];
    int i = blockIdx.x * 256 + threadIdx.x;
    sh[threadIdx.x] = (i < N) ? deg[i] : 0;
    __syncthreads();
    for (int st = 128; st > 0; st >>= 1) {
        if (threadIdx.x < st) sh[threadIdx.x] += sh[threadIdx.x + st];
        __syncthreads();
    }
    if (threadIdx.x == 0) part[blockIdx.x] = sh[0];
}

__global__ void k_scanpart(int* __restrict__ part, int nb) {
    __shared__ int sh[256];
    int v = (threadIdx.x < nb) ? part[threadIdx.x] : 0;
    sh[threadIdx.x] = v;
    __syncthreads();
    for (int st = 1; st < 256; st <<= 1) {
        int t = (threadIdx.x >= st) ? sh[threadIdx.x - st] : 0;
        __syncthreads();
        sh[threadIdx.x] += t;
        __syncthreads();
    }
    if (threadIdx.x < nb) part[threadIdx.x] = sh[threadIdx.x] - v;
}

__global__ void k_scanfinal(const int* __restrict__ deg, const int* __restrict__ part,
                            int* __restrict__ offs, int N, int E) {
    __shared__ int sh[256];
    int i = blockIdx.x * 256 + threadIdx.x;
    int v = (i < N) ? deg[i] : 0;
    sh[threadIdx.x] = v;
    __syncthreads();
    for (int st = 1; st < 256; st <<= 1) {
        int t = (threadIdx.x >= st) ? sh[threadIdx.x - st] : 0;
        __syncthreads();
        sh[threadIdx.x] += t;
        __syncthreads();
    }
    if (i < N) offs[i] = part[blockIdx.x] + sh[threadIdx.x] - v;
    if (i == 0) offs[N] = E;
}

// ---------------- counting-sort scatter: sorted_src grouped by dst ----------------
__global__ void k_scatter(const int* __restrict__ src, const int* __restrict__ dst,
                          const int* __restrict__ offs, int* __restrict__ cursor,
                          int* __restrict__ ssrc, int E) {
    int e = blockIdx.x * blockDim.x + threadIdx.x;
    if (e >= E) return;
    int d = dst[e];
    int p = offs[d] + atomicAdd(&cursor[d], 1);
    ssrc[p] = src[e];
}

// ---------------- register-blocked GEMM: C[M,256] = (A[M,K]@W[K,256]+bias)*rowscale? ----------------
// 64-row x 256-col tile, 256 threads, each thread 16 rows x 4 cols.
// As staged transposed [k][m] -> a-frag read is wave-broadcast ds_read_b128.
template<int K>
__global__ __launch_bounds__(256) void k_gemm64(const float* __restrict__ A,
        const float* __restrict__ W, const float* __restrict__ bias,
        const float* __restrict__ rowscale, float* __restrict__ C, int M) {
    __shared__ float As[32 * 64];   // [k][m]
    __shared__ float Bs[32 * 256];  // [k][n]
    const int tid = threadIdx.x;
    const int tc = tid & 63;        // cols tc*4 .. tc*4+3
    const int tr = tid >> 6;        // rows tr*16 .. tr*16+15
    const int m0 = blockIdx.x * 64;
    const int rows = (M - m0 < 64) ? (M - m0) : 64;

    float acc[16][4];
#pragma unroll
    for (int r = 0; r < 16; ++r)
#pragma unroll
        for (int c = 0; c < 4; ++c) acc[r][c] = 0.f;

    const int arow = tid & 63;
    const int akq = tid >> 6;
    float4* As4 = reinterpret_cast<float4*>(As);
    float4* Bs4 = reinterpret_cast<float4*>(Bs);

    for (int kc = 0; kc < K; kc += 32) {
        __syncthreads();
        // A chunk transposed: As[k][m] = A[m0+m][kc+k]
#pragma unroll
        for (int it = 0; it < 2; ++it) {
            int kq = akq + it * 4;   // 0..7
            float4 v = make_float4(0.f, 0.f, 0.f, 0.f);
            if (arow < rows)
                v = *reinterpret_cast<const float4*>(A + (size_t)(m0 + arow) * K + kc + kq * 4);
            As[(kq * 4 + 0) * 64 + arow] = v.x;
            As[(kq * 4 + 1) * 64 + arow] = v.y;
            As[(kq * 4 + 2) * 64 + arow] = v.z;
            As[(kq * 4 + 3) * 64 + arow] = v.w;
        }
        // B chunk: Bs[k][n] row-major, coalesced
        const float4* W4 = reinterpret_cast<const float4*>(W + (size_t)kc * 256);
#pragma unroll
        for (int it = 0; it < 8; ++it)
            Bs4[tid + it * 256] = W4[tid + it * 256];
        __syncthreads();
#pragma unroll 8
        for (int kk = 0; kk < 32; ++kk) {
            float4 b = Bs4[kk * 64 + tc];
#pragma unroll
            for (int u = 0; u < 4; ++u) {
                float4 a = As4[kk * 16 + tr * 4 + u];  // broadcast
                acc[u * 4 + 0][0] = fmaf(a.x, b.x, acc[u * 4 + 0][0]);
                acc[u * 4 + 0][1] = fmaf(a.x, b.y, acc[u * 4 + 0][1]);
                acc[u * 4 + 0][2] = fmaf(a.x, b.z, acc[u * 4 + 0][2]);
                acc[u * 4 + 0][3] = fmaf(a.x, b.w, acc[u * 4 + 0][3]);
                acc[u * 4 + 1][0] = fmaf(a.y, b.x, acc[u * 4 + 1][0]);
                acc[u * 4 + 1][1] = fmaf(a.y, b.y, acc[u * 4 + 1][1]);
                acc[u * 4 + 1][2] = fmaf(a.y, b.z, acc[u * 4 + 1][2]);
                acc[u * 4 + 1][3] = fmaf(a.y, b.w, acc[u * 4 + 1][3]);
                acc[u * 4 + 2][0] = fmaf(a.z, b.x, acc[u * 4 + 2][0]);
                acc[u * 4 + 2][1] = fmaf(a.z, b.y, acc[u * 4 + 2][1]);
                acc[u * 4 + 2][2] = fmaf(a.z, b.z, acc[u * 4 + 2][2]);
                acc[u * 4 + 2][3] = fmaf(a.z, b.w, acc[u * 4 + 2][3]);
                acc[u * 4 + 3][0] = fmaf(a.w, b.x, acc[u * 4 + 3][0]);
                acc[u * 4 + 3][1] = fmaf(a.w, b.y, acc[u * 4 + 3][1]);
                acc[u * 4 + 3][2] = fmaf(a.w, b.z, acc[u * 4 + 3][2]);
                acc[u * 4 + 3][3] = fmaf(a.w, b.w, acc[u * 4 + 3][3]);
            }
        }
    }

    float4 bv = *reinterpret_cast<const float4*>(bias + tc * 4);
#pragma unroll
    for (int r = 0; r < 16; ++r) {
        int lrow = tr * 16 + r;
        if (lrow < rows) {
            float4 v;
            v.x = acc[r][0] + bv.x;
            v.y = acc[r][1] + bv.y;
            v.z = acc[r][2] + bv.z;
            v.w = acc[r][3] + bv.w;
            if (rowscale) {
                float s = rowscale[m0 + lrow];
                v.x *= s; v.y *= s; v.z *= s; v.w *= s;
            }
            *reinterpret_cast<float4*>(C + (size_t)(m0 + lrow) * 256 + tc * 4) = v;
        }
    }
}

// ---------------- gather aggregation: out[d] = post(dinv[d] * (Ys[d] + sum_bucket Ys[s])) ----------------
__global__ __launch_bounds__(256) void k_gather_agg(const float* __restrict__ Ys,
        const int* __restrict__ offs, const int* __restrict__ ssrc,
        const float* __restrict__ dinv, float* __restrict__ outp, int N, int relu) {
    int wid = threadIdx.x >> 6, lane = threadIdx.x & 63;
    int d = blockIdx.x * 4 + wid;
    if (d >= N) return;
    int beg = offs[d], end = offs[d + 1];
    float4 acc = reinterpret_cast<const float4*>(Ys + (size_t)d * 256)[lane];  // self loop
    int i = beg;
    for (; i + 8 <= end; i += 8) {
        int s0 = ssrc[i], s1 = ssrc[i + 1], s2 = ssrc[i + 2], s3 = ssrc[i + 3];
        int s4 = ssrc[i + 4], s5 = ssrc[i + 5], s6 = ssrc[i + 6], s7 = ssrc[i + 7];
        float4 v0 = reinterpret_cast<const float4*>(Ys + (size_t)s0 * 256)[lane];
        float4 v1 = reinterpret_cast<const float4*>(Ys + (size_t)s1 * 256)[lane];
        float4 v2 = reinterpret_cast<const float4*>(Ys + (size_t)s2 * 256)[lane];
        float4 v3 = reinterpret_cast<const float4*>(Ys + (size_t)s3 * 256)[lane];
        float4 v4 = reinterpret_cast<const float4*>(Ys + (size_t)s4 * 256)[lane];
        float4 v5 = reinterpret_cast<const float4*>(Ys + (size_t)s5 * 256)[lane];
        float4 v6 = reinterpret_cast<const float4*>(Ys + (size_t)s6 * 256)[lane];
        float4 v7 = reinterpret_cast<const float4*>(Ys + (size_t)s7 * 256)[lane];
        acc.x += ((v0.x + v1.x) + (v2.x + v3.x)) + ((v4.x + v5.x) + (v6.x + v7.x));
        acc.y += ((v0.y + v1.y) + (v2.y + v3.y)) + ((v4.y + v5.y) + (v6.y + v7.y));
        acc.z += ((v0.z + v1.z) + (v2.z + v3.z)) + ((v4.z + v5.z) + (v6.z + v7.z));
        acc.w += ((v0.w + v1.w) + (v2.w + v3.w)) + ((v4.w + v5.w) + (v6.w + v7.w));
    }
    for (; i < end; ++i) {
        int s = ssrc[i];
        float4 v = reinterpret_cast<const float4*>(Ys + (size_t)s * 256)[lane];
        acc.x += v.x; acc.y += v.y; acc.z += v.z; acc.w += v.w;
    }
    float sc = dinv[d];
    acc.x *= sc; acc.y *= sc; acc.z *= sc; acc.w *= sc;
    if (relu) {
        acc.x = fmaxf(acc.x, 0.f); acc.y = fmaxf(acc.y, 0.f);
        acc.z = fmaxf(acc.z, 0.f); acc.w = fmaxf(acc.w, 0.f);
    }
    reinterpret_cast<float4*>(outp + (size_t)d * 256)[lane] = acc;
}

// ---------------- transpose 256x256: Wout[k][j] = Win[j][k] ----------------
__global__ void k_transpose256(const float* __restrict__ Win, float* __restrict__ Wout) {
    int j = threadIdx.x, k = blockIdx.x;
    Wout[k * 256 + j] = Win[j * 256 + k];
}

// ---------------- wsum[c] = sum_j opw[j][c];  bsum = sum(opb) ----------------
__global__ void k_wsum(const float* __restrict__ opw, const float* __restrict__ opb,
                       float* __restrict__ wsum, float* __restrict__ bsum) {
    int c = threadIdx.x;
    float s = 0.f;
    for (int j = 0; j < 256; ++j) s += opw[j * 256 + c];
    wsum[c] = s;
    __shared__ float red[256];
    red[c] = opb[c];
    __syncthreads();
    for (int st = 128; st > 0; st >>= 1) {
        if (c < st) red[c] += red[c + st];
        __syncthreads();
    }
    if (c == 0) *bsum = red[0];
}

// ---------------- wv_eff[h][k] = sum_{c in head h} wsum[h*64+c] * Wv[h*64+c][k] ----------------
__global__ void k_wveff(const float* __restrict__ ipw, const float* __restrict__ ipb,
                        const float* __restrict__ wsum, float* __restrict__ wv_eff,
                        float* __restrict__ vconst) {
    int h = blockIdx.x, k = threadIdx.x;
    float s = 0.f;
    for (int c = 0; c < 64; ++c)
        s += wsum[h * 64 + c] * ipw[(size_t)(512 + h * 64 + c) * 256 + k];
    wv_eff[h * 256 + k] = s;
    if (k == 0) {
        float t = 0.f;
        for (int c = 0; c < 64; ++c) t += ipb[512 + h * 64 + c] * wsum[h * 64 + c];
        vconst[h] = t;
    }
}

// ---------------- per-node: qk_self[n][h], vw[n][h] ----------------
__global__ void k_node_aux(const float* __restrict__ Q, const float* __restrict__ Km,
                           const float* __restrict__ Z, const float* __restrict__ wv_eff,
                           const float* __restrict__ vconst,
                           float* __restrict__ qk_self, float* __restrict__ vw, int N) {
    int wid = threadIdx.x >> 6, lane = threadIdx.x & 63;
    int n = blockIdx.x * 4 + wid;
    if (n >= N) return;
    float4 q = reinterpret_cast<const float4*>(Q + (size_t)n * 256)[lane];
    float4 k = reinterpret_cast<const float4*>(Km + (size_t)n * 256)[lane];
    float4 z = reinterpret_cast<const float4*>(Z + (size_t)n * 256)[lane];
    float p = q.x * k.x + q.y * k.y + q.z * k.z + q.w * k.w;
    for (int st = 1; st < 16; st <<= 1) p += __shfl_xor(p, st);
    if ((lane & 15) == 0) qk_self[n * 4 + (lane >> 4)] = p;

    float ph0, ph1, ph2, ph3;
    {
        float4 w;
        w = reinterpret_cast<const float4*>(wv_eff + 0 * 256)[lane];
        ph0 = z.x * w.x + z.y * w.y + z.z * w.z + z.w * w.w;
        w = reinterpret_cast<const float4*>(wv_eff + 1 * 256)[lane];
        ph1 = z.x * w.x + z.y * w.y + z.z * w.z + z.w * w.w;
        w = reinterpret_cast<const float4*>(wv_eff + 2 * 256)[lane];
        ph2 = z.x * w.x + z.y * w.y + z.z * w.z + z.w * w.w;
        w = reinterpret_cast<const float4*>(wv_eff + 3 * 256)[lane];
        ph3 = z.x * w.x + z.y * w.y + z.z * w.z + z.w * w.w;
    }
    for (int st = 1; st < 64; st <<= 1) {
        ph0 += __shfl_xor(ph0, st);
        ph1 += __shfl_xor(ph1, st);
        ph2 += __shfl_xor(ph2, st);
        ph3 += __shfl_xor(ph3, st);
    }
    if (lane == 0) {
        vw[n * 4 + 0] = ph0 + vconst[0];
        vw[n * 4 + 1] = ph1 + vconst[1];
        vw[n * 4 + 2] = ph2 + vconst[2];
        vw[n * 4 + 3] = ph3 + vconst[3];
    }
}

// ---------------- per pred-edge final ----------------
__global__ void k_edge_pred(const float* __restrict__ Q, const float* __restrict__ Km,
                            const float* __restrict__ qk_self, const float* __restrict__ vw,
                            const float* __restrict__ bsum, const int* __restrict__ sp,
                            const int* __restrict__ dp, float* __restrict__ out, int E) {
    int wid = threadIdx.x >> 6, lane = threadIdx.x & 63;
    int e = blockIdx.x * 4 + wid;
    if (e >= E) return;
    int s = sp[e], d = dp[e];
    float4 q = reinterpret_cast<const float4*>(Q + (size_t)s * 256)[lane];
    float4 k = reinterpret_cast<const float4*>(Km + (size_t)d * 256)[lane];
    float p = q.x * k.x + q.y * k.y + q.z * k.z + q.w * k.w;
    for (int st = 1; st < 16; st <<= 1) p += __shfl_xor(p, st);
    int h = lane >> 4;
    const float scale = 0.125f;
    float s1 = p * scale;
    float s0 = qk_self[s * 4 + h] * scale;
    float vs = vw[s * 4 + h], vd = vw[d * 4 + h];
    float m = fmaxf(s0, s1);
    float e0 = expf(s0 - m), e1 = expf(s1 - m);
    float contrib = (e0 * vs + e1 * vd) / (e0 + e1);
    contrib += __shfl_xor(contrib, 16);
    contrib += __shfl_xor(contrib, 32);
    if (lane == 0) out[e] = 1.f / (1.f + expf(-(contrib + *bsum)));
}

extern "C" void kernel_launch(void* const* d_in, const int* in_sizes, int n_in,
                              void* d_out, int out_size, void* d_ws, size_t ws_size,
                              hipStream_t stream) {
    const float* x   = (const float*)d_in[0];
    const int*   ei  = (const int*)d_in[1];
    const int*   eip = (const int*)d_in[2];
    const float* W1  = (const float*)d_in[3];
    const float* b1  = (const float*)d_in[4];
    const float* W2  = (const float*)d_in[5];
    const float* b2  = (const float*)d_in[6];
    const float* ipw = (const float*)d_in[7];
    const float* ipb = (const float*)d_in[8];
    const float* opw = (const float*)d_in[9];
    const float* opb = (const float*)d_in[10];
    float* out = (float*)d_out;

    const int N = in_sizes[0] / IN_CH;      // 50000
    const int E = in_sizes[1] / 2;          // 1.6M
    const int EP = in_sizes[2] / 2;         // 500K

    // workspace layout (floats), 16B alignment for float4 arrays
    float* wsf = (float*)d_ws;
    size_t o = 0;
    auto pad4 = [&](size_t v) { return (v + 3) & ~(size_t)3; };
    int*   deg     = (int*)(wsf + o); o += pad4(N);
    float* dinv    = wsf + o; o += pad4(N);
    float* wsum    = wsf + o; o += 256;
    float* bsum    = wsf + o; o += 4;
    float* wv_eff  = wsf + o; o += 1024;
    float* vconst  = wsf + o; o += 4;
    float* Wqt     = wsf + o; o += 256 * 256;
    float* Wkt     = wsf + o; o += 256 * 256;
    float* qk_self = wsf + o; o += pad4((size_t)4 * N);
    float* vw      = wsf + o; o += pad4((size_t)4 * N);
    int*   offs    = (int*)(wsf + o); o += pad4((size_t)N + 1);
    int*   cursor  = (int*)(wsf + o); o += pad4(N);
    int*   part    = (int*)(wsf + o); o += 256;
    int*   ssrc    = (int*)(wsf + o); o += pad4(E);
    float* A       = wsf + o; o += (size_t)N * 256;
    float* B       = wsf + o; o += (size_t)N * 256;
    float* Cb      = wsf + o; o += (size_t)N * 256;
    (void)ws_size; (void)n_in; (void)out_size;

    const int* src = ei;
    const int* dst = ei + E;
    const int nb = (N + 255) / 256;

    // ---- degree + dinv + CSR build (counting sort by dst) ----
    hipMemsetAsync(deg, 0, (size_t)N * 4, stream);
    hipMemsetAsync(cursor, 0, (size_t)N * 4, stream);
    k_deg<<<(E + 255) / 256, 256, 0, stream>>>(dst, deg, E);
    k_dinv<<<nb, 256, 0, stream>>>(deg, dinv, N);
    k_chunksum<<<nb, 256, 0, stream>>>(deg, part, N);
    k_scanpart<<<1, 256, 0, stream>>>(part, nb);
    k_scanfinal<<<nb, 256, 0, stream>>>(deg, part, offs, N, E);
    k_scatter<<<(E + 255) / 256, 256, 0, stream>>>(src, dst, offs, cursor, ssrc, E);

    // small precomputes (independent of GCN)
    k_transpose256<<<256, 256, 0, stream>>>(ipw, Wqt);
    k_transpose256<<<256, 256, 0, stream>>>(ipw + 256 * 256, Wkt);
    k_wsum<<<1, 256, 0, stream>>>(opw, opb, wsum, bsum);
    k_wveff<<<4, 256, 0, stream>>>(ipw, ipb, wsum, wv_eff, vconst);

    const int gBlocks = (N + 63) / 64;
    const int aBlocks = (N + 3) / 4;

    // ---- layer 1:  A = dinv*(x@W1+b1);  B = relu(dinv[d]*(A[d] + sum A[s])) ----
    k_gemm64<128><<<gBlocks, 256, 0, stream>>>(x, W1, b1, dinv, A, N);
    k_gather_agg<<<aBlocks, 256, 0, stream>>>(A, offs, ssrc, dinv, B, N, 1);

    // ---- layer 2:  Cb = dinv*(B@W2+b2);  A = z ----
    k_gemm64<256><<<gBlocks, 256, 0, stream>>>(B, W2, b2, dinv, Cb, N);
    k_gather_agg<<<aBlocks, 256, 0, stream>>>(Cb, offs, ssrc, dinv, A, N, 0);

    // ---- attention precompute: B = Q, Cb = K ----
    k_gemm64<256><<<gBlocks, 256, 0, stream>>>(A, Wqt, ipb, nullptr, B, N);
    k_gemm64<256><<<gBlocks, 256, 0, stream>>>(A, Wkt, ipb + 256, nullptr, Cb, N);
    k_node_aux<<<aBlocks, 256, 0, stream>>>(B, Cb, A, wv_eff, vconst, qk_self, vw, N);

    // ---- per pred edge ----
    k_edge_pred<<<(EP + 3) / 4, 256, 0, stream>>>(B, Cb, qk_self, vw, bsum,
                                                  eip, eip + EP, out, EP);
}